// Round 13
// baseline (368.438 us; speedup 1.0000x reference)
//
#include <hip/hip_runtime.h>
#include <hip/hip_bf16.h>
#include <cmath>

// Problem dims (fixed)
#define CB 128   // B
#define CL 50    // L
#define CN 12    // N == N2
#define CS 20    // S
#define CM 12    // M
#define CD 100   // D

typedef __attribute__((ext_vector_type(8))) short short8;
typedef __attribute__((ext_vector_type(4))) float f32x4;

__device__ __forceinline__ unsigned short f2bf(float f) {
    unsigned int u = __float_as_uint(f);
    u += 0x7FFFu + ((u >> 16) & 1u);     // round-to-nearest-even
    return (unsigned short)(u >> 16);
}
__device__ __forceinline__ float4 mul4(float4 a, float4 b) {
    return make_float4(a.x * b.x, a.y * b.y, a.z * b.z, a.w * b.w);
}
__device__ __forceinline__ float4 add4(float4 a, float4 b) {
    return make_float4(a.x + b.x, a.y + b.y, a.z + b.z, a.w + b.w);
}
// pack 8 fp32 -> 8 bf16 via v_cvt_pk_bf16_f32 (RNE, identical to manual path)
__device__ __forceinline__ short8 pack8(float4 a, float4 b) {
    union { short8 s; __hip_bfloat162 h[4]; } u;
    u.h[0] = __float22bfloat162_rn(make_float2(a.x, a.y));
    u.h[1] = __float22bfloat162_rn(make_float2(a.z, a.w));
    u.h[2] = __float22bfloat162_rn(make_float2(b.x, b.y));
    u.h[3] = __float22bfloat162_rn(make_float2(b.z, b.w));
    return u.s;
}

// ---------------------------------------------------------------------------
// Weight prep: transpose + pad + bf16-convert.
// ---------------------------------------------------------------------------
__global__ void prep_weights_kernel(const float* __restrict__ w1,
                                    const float* __restrict__ w3,
                                    unsigned short* __restrict__ w1t,
                                    unsigned short* __restrict__ w3t)
{
    int idx = blockIdx.x * 256 + threadIdx.x;
    const int TOT1 = 2 * 112 * 128;   // 28672
    const int TOT3 = 2 * 112 * 224;   // 50176
    if (idx < TOT1) {
        int l = idx / (112 * 128);
        int r = idx - l * (112 * 128);
        int n = r / 128, k = r - (r / 128) * 128;
        float v = (n < CD && k < CD) ? w1[l * CD * CD + k * CD + n] : 0.f;
        w1t[idx] = f2bf(v);
    } else if (idx < TOT1 + TOT3) {
        int j = idx - TOT1;
        int l = j / (112 * 224);
        int r = j - l * (112 * 224);
        int n = r / 224, k = r - (r / 224) * 224;
        float v = (n < CD && k < 2 * CD) ? w3[l * 2 * CD * CD + k * CD + n] : 0.f;
        w3t[j] = f2bf(v);
    }
}

// ---------------------------------------------------------------------------
// Neigh-attention wave body (R12-verified): 2 groups/wave, single acc live,
// register softmax, T14 epilogue prefetch for group 0. sB must hold the
// XOR-swizzled layer weights already? No: this body stages sB itself.
// ---------------------------------------------------------------------------
__device__ __forceinline__ void neigh_body(
    const float* __restrict__ ap, const float* __restrict__ cp,
    float* __restrict__ op, int l2f, int g0,
    const unsigned short* __restrict__ w1t, const float* __restrict__ w2,
    unsigned short* sB, int tid)
{
    const int wave = tid >> 6, lane = tid & 63;
    const int lhi = lane >> 4, llo = lane & 15;

    // ---- stage B (weights, XOR-swizzled; 16 quads/row) ----
    for (int i = tid; i < 1792; i += 256) {           // 112 rows x 16 chunks
        int n = i >> 4, kc = i & 15;
        short8 v = *(const short8*)(w1t + n * 128 + kc * 8);
        char* dst = (char*)sB + n * 256 + ((kc ^ (n & 7)) << 4);
        *(short8*)dst = v;
    }

    // ---- A fragments straight from global into regs (overlap B staging) ----
    short8 af[2][4];
#pragma unroll
    for (int mt = 0; mt < 2; ++mt) {
        const int g = g0 + wave * 2 + mt;
        const int n = (llo < CN) ? llo : 0;           // clamp pad rows
        const float* cpr = cp + ((size_t)g * CN + n) * CD;
        const float* apr = ap + (size_t)g * CD;
#pragma unroll
        for (int ks = 0; ks < 4; ++ks) {
            const int k0 = ks * 32 + lhi * 8;
            if (ks < 3) {
                float4 cv0 = *(const float4*)(cpr + k0);
                float4 cv1 = *(const float4*)(cpr + k0 + 4);
                float4 av0 = *(const float4*)(apr + k0);
                float4 av1 = *(const float4*)(apr + k0 + 4);
                af[mt][ks] = pack8(mul4(av0, cv0), mul4(av1, cv1));
            } else if (lhi == 0) {                    // k = 96..103 (partial)
                float4 cv0 = *(const float4*)(cpr + 96);
                float4 av0 = *(const float4*)(apr + 96);
                float4 z = make_float4(0.f, 0.f, 0.f, 0.f);
                af[mt][ks] = pack8(mul4(av0, cv0), z);
            } else {
                af[mt][ks] = (short8){0, 0, 0, 0, 0, 0, 0, 0};
            }
        }
    }
    __syncthreads();    // the ONLY block barrier: sB visible to all waves

    // ---- T14: issue group-0 epilogue loads NOW (post-barrier, pre-MFMA) ----
    const bool act = lane < 50;
    const int d2 = act ? lane * 2 : 0;    // clamped addr, no result-select
    float2 epi0[CN];
    {
        const float* crow = cp + (size_t)(g0 + wave * 2) * CN * CD + d2;
#pragma unroll
        for (int n = 0; n < CN; ++n)
            epi0[n] = *(const float2*)(crow + n * CD);
    }

    const char* pB = (const char*)sB;
    const int bxor = llo & 7;

    // ---- per-group: MFMA (single acc live) -> scores -> register softmax ----
    float att[2][4];
#pragma unroll
    for (int mt = 0; mt < 2; ++mt) {
        f32x4 acc[7];
#pragma unroll
        for (int nt = 0; nt < 7; ++nt) acc[nt] = (f32x4){0.f, 0.f, 0.f, 0.f};
#pragma unroll
        for (int ks = 0; ks < 4; ++ks) {
            const int kbq = ks * 4 + lhi;
#pragma unroll
            for (int nt = 0; nt < 7; ++nt) {
                short8 bfv = *(const short8*)(pB + (nt * 16 + llo) * 256 + ((kbq ^ bxor) << 4));
                acc[nt] = __builtin_amdgcn_mfma_f32_16x16x32_bf16(af[mt][ks], bfv, acc[nt], 0, 0, 0);
            }
        }

        float s[4] = {0.f, 0.f, 0.f, 0.f};
#pragma unroll
        for (int nt = 0; nt < 7; ++nt) {
            const int n = nt * 16 + llo;
            const float w2v = (n < CD) ? w2[n] : 0.f;
#pragma unroll
            for (int r = 0; r < 4; ++r) {
                float y = acc[nt][r];
                y = (y >= 0.f) ? y : 0.2f * y;
                s[r] = fmaf(y, w2v, s[r]);
            }
        }
#pragma unroll
        for (int off = 1; off < 16; off <<= 1)
#pragma unroll
            for (int r = 0; r < 4; ++r) s[r] += __shfl_xor(s[r], off, 64);
        float pmax = -1e30f;
        if (lhi < 3) pmax = fmaxf(fmaxf(s[0], s[1]), fmaxf(s[2], s[3]));
        pmax = fmaxf(pmax, __shfl_xor(pmax, 16, 64));
        pmax = fmaxf(pmax, __shfl_xor(pmax, 32, 64));
        float e[4];
#pragma unroll
        for (int r = 0; r < 4; ++r) e[r] = (lhi < 3) ? __expf(s[r] - pmax) : 0.f;
        float ps = e[0] + e[1] + e[2] + e[3];
        ps += __shfl_xor(ps, 16, 64);
        ps += __shfl_xor(ps, 32, 64);
        const float inv = 1.f / ps;
#pragma unroll
        for (int r = 0; r < 4; ++r) att[mt][r] = e[r] * inv;
    }

    // ---- epilogue: weighted sum; group 0 from prefetched regs ----
#pragma unroll
    for (int mt = 0; mt < 2; ++mt) {
        const int g = g0 + wave * 2 + mt;
        float2 tot = make_float2(0.f, 0.f);
        {
            const float* crow = cp + (size_t)g * CN * CD + d2;
#pragma unroll
            for (int n = 0; n < CN; ++n) {
                const float at = __shfl(att[mt][n & 3], (n >> 2) * 16, 64);
                float2 cv = (mt == 0) ? epi0[n] : *(const float2*)(crow + n * CD);
                tot.x = fmaf(at, cv.x, tot.x);
                tot.y = fmaf(at, cv.y, tot.y);
            }
        }
        if (l2f) {
            float sq = act ? (tot.x * tot.x + tot.y * tot.y) : 0.f;
#pragma unroll
            for (int off = 32; off > 0; off >>= 1) sq += __shfl_xor(sq, off, 64);
            const float rn = 1.f / fmaxf(sqrtf(sq), 1e-12f);
            tot.x *= rn; tot.y *= rn;
        }
        if (act) *(float2*)(op + (size_t)g * CD + d2) = tot;
    }
}

// ---------------------------------------------------------------------------
// Tar-attention wave body (R12-verified): 1 group/wave, K=224, reg softmax.
// ---------------------------------------------------------------------------
__device__ __forceinline__ int swzq28(int q, int x) {
    return q ^ ((q < 24) ? x : (x & 3));
}
__device__ __forceinline__ float4 xchunk(const float* __restrict__ tnr,
                                         const float* __restrict__ tv,
                                         const float* __restrict__ slv, int k) {
    if (k < CD)
        return mul4(*(const float4*)(tv + k), *(const float4*)(tnr + k));
    if (k < 2 * CD) {
        int k2 = k - CD;
        return add4(*(const float4*)(slv + k2), *(const float4*)(tnr + k2));
    }
    return make_float4(0.f, 0.f, 0.f, 0.f);
}

__device__ __forceinline__ void tar_body(
    const float* __restrict__ tvec, const float* __restrict__ sl,
    const float* __restrict__ tn, const unsigned short* __restrict__ w3t,
    const float* __restrict__ w4, const float* __restrict__ tar0,
    float* __restrict__ outp, int slStride, int g,
    unsigned short* sB, int tid)
{
    const int wave = tid >> 6, lane = tid & 63;
    const int lhi = lane >> 4, llo = lane & 15;
    const int b = g / CS;

    // ---- stage B ----
    for (int i = tid; i < 3136; i += 256) {           // 112 rows x 28 chunks
        int n = i / 28, kc = i - (i / 28) * 28;
        short8 v = *(const short8*)(w3t + n * 224 + kc * 8);
        char* dst = (char*)sB + n * 448 + (swzq28(kc, n & 7) << 4);
        *(short8*)dst = v;
    }

    // ---- A fragments in registers ----
    short8 af[7];
    {
        const int m = (llo < CM) ? llo : 0;
        const float* tnr = tn + ((size_t)g * CM + m) * CD;
        const float* tv = tvec + (size_t)g * CD;
        const float* slv = sl + (size_t)b * slStride;
#pragma unroll
        for (int ks = 0; ks < 7; ++ks) {
            const int k0 = ks * 32 + lhi * 8;
            af[ks] = pack8(xchunk(tnr, tv, slv, k0),
                           xchunk(tnr, tv, slv, k0 + 4));
        }
    }
    __syncthreads();    // the ONLY block barrier

    // ---- MFMA: K = 224 (7 k-steps), B frags just-in-time ----
    f32x4 acc[7];
#pragma unroll
    for (int nt = 0; nt < 7; ++nt) acc[nt] = (f32x4){0.f, 0.f, 0.f, 0.f};

    const char* pB = (const char*)sB;
    const int bxor = llo & 7;
#pragma unroll
    for (int ks = 0; ks < 7; ++ks) {
        const int kbq = ks * 4 + lhi;                 // 0..27
#pragma unroll
        for (int nt = 0; nt < 7; ++nt) {
            short8 bfv = *(const short8*)(pB + (nt * 16 + llo) * 448 + (swzq28(kbq, bxor) << 4));
            acc[nt] = __builtin_amdgcn_mfma_f32_16x16x32_bf16(af[ks], bfv, acc[nt], 0, 0, 0);
        }
    }

    // ---- scores: tanh + dot w4, reduce across the 16 col-lanes ----
    float s[4] = {0.f, 0.f, 0.f, 0.f};
#pragma unroll
    for (int nt = 0; nt < 7; ++nt) {
        const int n = nt * 16 + llo;
        const float w4v = (n < CD) ? w4[n] : 0.f;
#pragma unroll
        for (int r = 0; r < 4; ++r)
            s[r] = fmaf(tanhf(acc[nt][r]), w4v, s[r]);
    }
#pragma unroll
    for (int off = 1; off < 16; off <<= 1)
#pragma unroll
        for (int r = 0; r < 4; ++r) s[r] += __shfl_xor(s[r], off, 64);

    // ---- register softmax over the 12 valid rows ----
    float pmax = -1e30f;
    if (lhi < 3) pmax = fmaxf(fmaxf(s[0], s[1]), fmaxf(s[2], s[3]));
    pmax = fmaxf(pmax, __shfl_xor(pmax, 16, 64));
    pmax = fmaxf(pmax, __shfl_xor(pmax, 32, 64));
    float e[4];
#pragma unroll
    for (int r = 0; r < 4; ++r) e[r] = (lhi < 3) ? __expf(s[r] - pmax) : 0.f;
    float ps = e[0] + e[1] + e[2] + e[3];
    ps += __shfl_xor(ps, 16, 64);
    ps += __shfl_xor(ps, 32, 64);
    const float inv = 1.f / ps;
    float att[4];
#pragma unroll
    for (int r = 0; r < 4; ++r) att[r] = e[r] * inv;

    // ---- epilogue: (sum att*tn + tar0)*0.5, l2norm, 50 lanes x float2 ----
    const bool act = lane < 50;
    const int d2 = lane * 2;
    float2 tot = make_float2(0.f, 0.f);
    if (act) {
        const float* tnr = tn + (size_t)g * CM * CD + d2;
#pragma unroll
        for (int m = 0; m < CM; ++m) {
            const float at = __shfl(att[m & 3], (m >> 2) * 16, 64);
            float2 cv = *(const float2*)(tnr + m * CD);
            tot.x = fmaf(at, cv.x, tot.x);
            tot.y = fmaf(at, cv.y, tot.y);
        }
        float2 t0 = *(const float2*)(tar0 + (size_t)g * CD + d2);
        tot.x = (tot.x + t0.x) * 0.5f;
        tot.y = (tot.y + t0.y) * 0.5f;
    }
    float sq = act ? (tot.x * tot.x + tot.y * tot.y) : 0.f;
#pragma unroll
    for (int off = 32; off > 0; off >>= 1) sq += __shfl_xor(sq, off, 64);
    const float rn = 1.f / fmaxf(sqrtf(sq), 1e-12f);
    if (act) {
        tot.x *= rn; tot.y *= rn;
        *(float2*)(outp + (size_t)g * CD + d2) = tot;
    }
}

// ---------------------------------------------------------------------------
// Big fused neighbor launch (unchanged R12): L0 session + 2-hop regions.
// ---------------------------------------------------------------------------
__global__ __launch_bounds__(256) void neigh_mfma_kernel(
    const float* __restrict__ a0, const float* __restrict__ c0,
    float* __restrict__ o0, int nb0, int l20,
    const float* __restrict__ a1, const float* __restrict__ c1,
    float* __restrict__ o1, int l21,
    const unsigned short* __restrict__ w1t,
    const float* __restrict__ w2)
{
    __shared__ __align__(16) unsigned short sB[112 * 128];  // 28 KB
    const int tid = threadIdx.x;
    const float *ap, *cp; float* op; int l2f, g0;
    if ((int)blockIdx.x < nb0) {
        ap = a0; cp = c0; op = o0; l2f = l20; g0 = blockIdx.x * 8;
    } else {
        ap = a1; cp = c1; op = o1; l2f = l21; g0 = (blockIdx.x - nb0) * 8;
    }
    neigh_body(ap, cp, op, l2f, g0, w1t, w2, sB, tid);
}

// ---------------------------------------------------------------------------
// Merged L1-session-neigh + tar0 dispatch (independent small kernels).
// blocks [0, nbN): neigh path (emb0, sn1 -> emb1, layer-1 weights)
// blocks [nbN, ..): tar0 path (tar_self, emb0[l=0] -> T1, layer-0 weights)
// Shared mem = union of both footprints (49 KB).
// ---------------------------------------------------------------------------
__global__ __launch_bounds__(256) void l1tar_kernel(
    const float* __restrict__ emb0, const float* __restrict__ sn1,
    float* __restrict__ emb1,
    const unsigned short* __restrict__ w1tL1, const float* __restrict__ w2L1,
    const float* __restrict__ tar_self, const float* __restrict__ tar_nb,
    const unsigned short* __restrict__ w3tL0, const float* __restrict__ w4L0,
    float* __restrict__ T1, int nbN)
{
    __shared__ __align__(16) union {
        unsigned short b1[112 * 128];   // neigh weights (28 KB)
        unsigned short b3[112 * 224];   // tar weights   (49 KB)
    } sU;
    const int tid = threadIdx.x;
    if ((int)blockIdx.x < nbN) {
        neigh_body(emb0, sn1, emb1, 1, blockIdx.x * 8, w1tL1, w2L1, sU.b1, tid);
    } else {
        const int g = (blockIdx.x - nbN) * 4 + (tid >> 6);
        tar_body(tar_self, emb0, tar_nb, w3tL0, w4L0, tar_self, T1,
                 CL * CD, g, sU.b3, tid);
    }
}

// ---------------------------------------------------------------------------
// Standalone tar kernel (for tar1, depends on T1).
// ---------------------------------------------------------------------------
__global__ __launch_bounds__(256) void tar_mfma_kernel(
    const float* __restrict__ tvec, const float* __restrict__ sl,
    const float* __restrict__ tn, const unsigned short* __restrict__ w3t,
    const float* __restrict__ w4, const float* __restrict__ tar0,
    float* __restrict__ outp, int slStride)
{
    __shared__ __align__(16) unsigned short sB[112 * 224];  // 49 KB
    const int tid = threadIdx.x;
    const int g = blockIdx.x * 4 + (tid >> 6);
    tar_body(tvec, sl, tn, w3t, w4, tar0, outp, slStride, g, sB, tid);
}

// ---------------------------------------------------------------------------
// Output assembly — nontemporal streaming stores (f32x4 native vector type).
// ---------------------------------------------------------------------------
__global__ void assemble_kernel(
    const float* __restrict__ sess_self, const float* __restrict__ emb0,
    const float* __restrict__ emb1, const float* __restrict__ tar_self,
    const float* __restrict__ T1, const float* __restrict__ T2,
    f32x4* __restrict__ out)
{
    const int LD4 = CL * CD / 4;          // 1250
    const int SLD4 = CS * LD4;            // 25000
    const int LAY0 = CB * SLD4;           // 3,200,000
    const int TOT0 = 3 * LAY0;            // 9,600,000
    const int LAY1 = CB * CS * CD / 4;    // 64,000
    const int TOT = TOT0 + 10 * LAY1;     // 10,240,000

    for (int i = blockIdx.x * blockDim.x + threadIdx.x; i < TOT;
         i += gridDim.x * blockDim.x) {
        f32x4 v;
        if (i < TOT0) {
            int layer = i / LAY0;
            int r = i - layer * LAY0;
            int b = r / SLD4;
            int r2 = r - b * SLD4;
            int ld4 = r2 % LD4;
            const float* src = (layer == 0) ? sess_self : (layer == 1) ? emb0 : emb1;
            v = ((const f32x4*)src)[b * LD4 + ld4];
        } else {
            int j = i - TOT0;
            int layer = j / LAY1;
            int r = j - layer * LAY1;
            int k = layer % 5;
            const float* src = (k == 4) ? T2 : ((k == 1) || (k == 3)) ? T1 : tar_self;
            v = ((const f32x4*)src)[r];
        }
        __builtin_nontemporal_store(v, &out[i]);
    }
}

extern "C" void kernel_launch(void* const* d_in, const int* in_sizes, int n_in,
                              void* d_out, int out_size, void* d_ws, size_t ws_size,
                              hipStream_t stream)
{
    const float* sess_self      = (const float*)d_in[0];
    const float* sess_neighbor  = (const float*)d_in[1];
    const float* sess_neighbor2 = (const float*)d_in[2];
    const float* tar_self       = (const float*)d_in[3];
    const float* tar_neighbor   = (const float*)d_in[4];
    const float* w1             = (const float*)d_in[5];  // [2, D, D]
    const float* w2             = (const float*)d_in[6];  // [2, D, 1]
    const float* w3             = (const float*)d_in[7];  // [2, 2D, D]
    const float* w4             = (const float*)d_in[8];  // [2, D, 1]
    float* out = (float*)d_out;
    float* ws  = (float*)d_ws;

    // workspace (floats): emb0 640k | emb1 640k | sn1 7.68M | T1 256k | T2 256k
    // then bf16 weights: w1t 28672 sh, w3t 50176 sh
    float* emb0 = ws;
    float* emb1 = ws + 640000;
    float* sn1  = ws + 1280000;
    float* T1   = ws + 8960000;
    float* T2   = ws + 9216000;
    unsigned short* w1t = (unsigned short*)(ws + 9472000);
    unsigned short* w3t = w1t + 28672;

    prep_weights_kernel<<<308, 256, 0, stream>>>(w1, w3, w1t, w3t);

    // merged launch (8 groups/block): L0 session attention (800 blocks, l2)
    // + 2-hop aggregation (9600 blocks) — both use layer-0 weights.
    neigh_mfma_kernel<<<10400, 256, 0, stream>>>(
        sess_self, sess_neighbor, emb0, 800, 1,
        sess_neighbor, sess_neighbor2, sn1, 0,
        w1t, w2);
    // merged: L1 session attention (800 blocks) + tar0 (640 blocks) — both
    // depend only on launch-2 outputs (emb0, sn1), independent of each other.
    l1tar_kernel<<<1440, 256, 0, stream>>>(
        emb0, sn1, emb1, w1t + 112 * 128, w2 + CD,
        tar_self, tar_neighbor, w3t, w4, T1, 800);
    // target attention layer 1: t = T1, sl = sess_self[b, 0, :]
    tar_mfma_kernel<<<640, 256, 0, stream>>>(
        T1, sess_self, tar_neighbor, w3t + 112 * 224, w4 + CD, tar_self, T2, CL * CD);

    assemble_kernel<<<2048, 256, 0, stream>>>(
        sess_self, emb0, emb1, tar_self, T1, T2, (f32x4*)out);
}

// Round 14
// 252.712 us; speedup vs baseline: 1.4579x; 1.4579x over previous
//
#include <hip/hip_runtime.h>
#include <hip/hip_bf16.h>
#include <cmath>

// Problem dims (fixed)
#define CB 128   // B
#define CL 50    // L
#define CN 12    // N == N2
#define CS 20    // S
#define CM 12    // M
#define CD 100   // D

typedef __attribute__((ext_vector_type(8))) short short8;
typedef __attribute__((ext_vector_type(4))) float f32x4;

__device__ __forceinline__ unsigned short f2bf(float f) {
    unsigned int u = __float_as_uint(f);
    u += 0x7FFFu + ((u >> 16) & 1u);     // round-to-nearest-even
    return (unsigned short)(u >> 16);
}
__device__ __forceinline__ float4 mul4(float4 a, float4 b) {
    return make_float4(a.x * b.x, a.y * b.y, a.z * b.z, a.w * b.w);
}
__device__ __forceinline__ float4 add4(float4 a, float4 b) {
    return make_float4(a.x + b.x, a.y + b.y, a.z + b.z, a.w + b.w);
}
// pack 8 fp32 -> 8 bf16 via v_cvt_pk_bf16_f32 (RNE, identical to manual path)
__device__ __forceinline__ short8 pack8(float4 a, float4 b) {
    union { short8 s; __hip_bfloat162 h[4]; } u;
    u.h[0] = __float22bfloat162_rn(make_float2(a.x, a.y));
    u.h[1] = __float22bfloat162_rn(make_float2(a.z, a.w));
    u.h[2] = __float22bfloat162_rn(make_float2(b.x, b.y));
    u.h[3] = __float22bfloat162_rn(make_float2(b.z, b.w));
    return u.s;
}

// ---------------------------------------------------------------------------
// Weight prep: transpose + pad + bf16-convert.
// ---------------------------------------------------------------------------
__global__ void prep_weights_kernel(const float* __restrict__ w1,
                                    const float* __restrict__ w3,
                                    unsigned short* __restrict__ w1t,
                                    unsigned short* __restrict__ w3t)
{
    int idx = blockIdx.x * 256 + threadIdx.x;
    const int TOT1 = 2 * 112 * 128;   // 28672
    const int TOT3 = 2 * 112 * 224;   // 50176
    if (idx < TOT1) {
        int l = idx / (112 * 128);
        int r = idx - l * (112 * 128);
        int n = r / 128, k = r - (r / 128) * 128;
        float v = (n < CD && k < CD) ? w1[l * CD * CD + k * CD + n] : 0.f;
        w1t[idx] = f2bf(v);
    } else if (idx < TOT1 + TOT3) {
        int j = idx - TOT1;
        int l = j / (112 * 224);
        int r = j - l * (112 * 224);
        int n = r / 224, k = r - (r / 224) * 224;
        float v = (n < CD && k < 2 * CD) ? w3[l * 2 * CD * CD + k * CD + n] : 0.f;
        w3t[j] = f2bf(v);
    }
}

// ---------------------------------------------------------------------------
// Fused neighbor attention: TWO groups per wave, 8 groups per block.
// Sequential per-group MFMA (single acc[7] live); register softmax.
// T14 (corrected): group-0 epilogue rows issued RIGHT AFTER the barrier,
// consumed after softmax — loads hide under MFMA/scores, no barrier drain.
// Two regions per launch (same weights): blockIdx < nb0 -> region 0.
// ---------------------------------------------------------------------------
__global__ __launch_bounds__(256) void neigh_mfma_kernel(
    const float* __restrict__ a0, const float* __restrict__ c0,
    float* __restrict__ o0, int nb0, int l20,
    const float* __restrict__ a1, const float* __restrict__ c1,
    float* __restrict__ o1, int l21,
    const unsigned short* __restrict__ w1t,   // [112][128] bf16
    const float* __restrict__ w2)             // [100]
{
    __shared__ __align__(16) unsigned short sB[112 * 128];  // 28 KB, 256B rows

    const int tid = threadIdx.x;
    const int wave = tid >> 6, lane = tid & 63;
    const int lhi = lane >> 4, llo = lane & 15;

    // region resolve (8 groups per block, 2 per wave)
    const float *ap, *cp; float* op; int l2f, g0;
    if ((int)blockIdx.x < nb0) {
        ap = a0; cp = c0; op = o0; l2f = l20; g0 = blockIdx.x * 8;
    } else {
        ap = a1; cp = c1; op = o1; l2f = l21; g0 = (blockIdx.x - nb0) * 8;
    }

    // ---- stage B (weights, XOR-swizzled; 16 quads/row) ----
    for (int i = tid; i < 1792; i += 256) {           // 112 rows x 16 chunks
        int n = i >> 4, kc = i & 15;
        short8 v = *(const short8*)(w1t + n * 128 + kc * 8);
        char* dst = (char*)sB + n * 256 + ((kc ^ (n & 7)) << 4);
        *(short8*)dst = v;
    }

    // ---- A fragments straight from global into regs (overlap B staging) ----
    short8 af[2][4];
#pragma unroll
    for (int mt = 0; mt < 2; ++mt) {
        const int g = g0 + wave * 2 + mt;
        const int n = (llo < CN) ? llo : 0;           // clamp pad rows
        const float* cpr = cp + ((size_t)g * CN + n) * CD;
        const float* apr = ap + (size_t)g * CD;
#pragma unroll
        for (int ks = 0; ks < 4; ++ks) {
            const int k0 = ks * 32 + lhi * 8;
            if (ks < 3) {
                float4 cv0 = *(const float4*)(cpr + k0);
                float4 cv1 = *(const float4*)(cpr + k0 + 4);
                float4 av0 = *(const float4*)(apr + k0);
                float4 av1 = *(const float4*)(apr + k0 + 4);
                af[mt][ks] = pack8(mul4(av0, cv0), mul4(av1, cv1));
            } else if (lhi == 0) {                    // k = 96..103 (partial)
                float4 cv0 = *(const float4*)(cpr + 96);
                float4 av0 = *(const float4*)(apr + 96);
                float4 z = make_float4(0.f, 0.f, 0.f, 0.f);
                af[mt][ks] = pack8(mul4(av0, cv0), z);
            } else {
                af[mt][ks] = (short8){0, 0, 0, 0, 0, 0, 0, 0};
            }
        }
    }
    __syncthreads();    // the ONLY block barrier: sB visible to all waves

    // ---- T14: issue group-0 epilogue loads NOW (post-barrier, pre-MFMA) ----
    const bool act = lane < 50;
    const int d2 = act ? lane * 2 : 0;    // clamped addr, no result-select
    float2 epi0[CN];
    {
        const float* crow = cp + (size_t)(g0 + wave * 2) * CN * CD + d2;
#pragma unroll
        for (int n = 0; n < CN; ++n)
            epi0[n] = *(const float2*)(crow + n * CD);
    }

    const char* pB = (const char*)sB;
    const int bxor = llo & 7;

    // ---- per-group: MFMA (single acc live) -> scores -> register softmax ----
    float att[2][4];
#pragma unroll
    for (int mt = 0; mt < 2; ++mt) {
        f32x4 acc[7];
#pragma unroll
        for (int nt = 0; nt < 7; ++nt) acc[nt] = (f32x4){0.f, 0.f, 0.f, 0.f};
#pragma unroll
        for (int ks = 0; ks < 4; ++ks) {
            const int kbq = ks * 4 + lhi;
#pragma unroll
            for (int nt = 0; nt < 7; ++nt) {
                short8 bfv = *(const short8*)(pB + (nt * 16 + llo) * 256 + ((kbq ^ bxor) << 4));
                acc[nt] = __builtin_amdgcn_mfma_f32_16x16x32_bf16(af[mt][ks], bfv, acc[nt], 0, 0, 0);
            }
        }

        float s[4] = {0.f, 0.f, 0.f, 0.f};
#pragma unroll
        for (int nt = 0; nt < 7; ++nt) {
            const int n = nt * 16 + llo;
            const float w2v = (n < CD) ? w2[n] : 0.f;
#pragma unroll
            for (int r = 0; r < 4; ++r) {
                float y = acc[nt][r];
                y = (y >= 0.f) ? y : 0.2f * y;
                s[r] = fmaf(y, w2v, s[r]);
            }
        }
#pragma unroll
        for (int off = 1; off < 16; off <<= 1)
#pragma unroll
            for (int r = 0; r < 4; ++r) s[r] += __shfl_xor(s[r], off, 64);
        // lanes now hold scores for rows lhi*4+r (rows >= 12 are pad)
        float pmax = -1e30f;
        if (lhi < 3) pmax = fmaxf(fmaxf(s[0], s[1]), fmaxf(s[2], s[3]));
        pmax = fmaxf(pmax, __shfl_xor(pmax, 16, 64));
        pmax = fmaxf(pmax, __shfl_xor(pmax, 32, 64));
        float e[4];
#pragma unroll
        for (int r = 0; r < 4; ++r) e[r] = (lhi < 3) ? __expf(s[r] - pmax) : 0.f;
        float ps = e[0] + e[1] + e[2] + e[3];
        ps += __shfl_xor(ps, 16, 64);
        ps += __shfl_xor(ps, 32, 64);
        const float inv = 1.f / ps;
#pragma unroll
        for (int r = 0; r < 4; ++r) att[mt][r] = e[r] * inv;
    }

    // ---- epilogue: weighted sum; group 0 from prefetched regs ----
#pragma unroll
    for (int mt = 0; mt < 2; ++mt) {
        const int g = g0 + wave * 2 + mt;
        float2 tot = make_float2(0.f, 0.f);
        {
            const float* crow = cp + (size_t)g * CN * CD + d2;
#pragma unroll
            for (int n = 0; n < CN; ++n) {
                const float at = __shfl(att[mt][n & 3], (n >> 2) * 16, 64);
                float2 cv = (mt == 0) ? epi0[n] : *(const float2*)(crow + n * CD);
                tot.x = fmaf(at, cv.x, tot.x);
                tot.y = fmaf(at, cv.y, tot.y);
            }
        }
        if (l2f) {
            float sq = act ? (tot.x * tot.x + tot.y * tot.y) : 0.f;
#pragma unroll
            for (int off = 32; off > 0; off >>= 1) sq += __shfl_xor(sq, off, 64);
            const float rn = 1.f / fmaxf(sqrtf(sq), 1e-12f);
            tot.x *= rn; tot.y *= rn;
        }
        if (act) *(float2*)(op + (size_t)g * CD + d2) = tot;
    }
}

// ---------------------------------------------------------------------------
// Fused target attention: ONE group per wave, 4 groups per block, K=224.
// (R8-verified structure; pack8 via cvt_pk.)
// ---------------------------------------------------------------------------
__device__ __forceinline__ int swzq28(int q, int x) {
    return q ^ ((q < 24) ? x : (x & 3));
}
__device__ __forceinline__ float4 xchunk(const float* __restrict__ tnr,
                                         const float* __restrict__ tv,
                                         const float* __restrict__ slv, int k) {
    if (k < CD)
        return mul4(*(const float4*)(tv + k), *(const float4*)(tnr + k));
    if (k < 2 * CD) {
        int k2 = k - CD;
        return add4(*(const float4*)(slv + k2), *(const float4*)(tnr + k2));
    }
    return make_float4(0.f, 0.f, 0.f, 0.f);
}

__global__ __launch_bounds__(256) void tar_mfma_kernel(
    const float* __restrict__ tvec,           // [2560, 100]
    const float* __restrict__ sl,             // per-b row, stride slStride
    const float* __restrict__ tn,             // [2560, 12, 100]
    const unsigned short* __restrict__ w3t,   // [112][224] bf16
    const float* __restrict__ w4,             // [100]
    const float* __restrict__ tar0,           // [2560, 100]
    float* __restrict__ outp,                 // [2560, 100]
    int slStride)
{
    __shared__ __align__(16) unsigned short sB[112 * 224];  // 49 KB, 448B rows

    const int tid = threadIdx.x;
    const int wave = tid >> 6, lane = tid & 63;
    const int lhi = lane >> 4, llo = lane & 15;
    const int g = blockIdx.x * 4 + wave;     // this wave's group
    const int b = g / CS;

    // ---- stage B ----
    for (int i = tid; i < 3136; i += 256) {           // 112 rows x 28 chunks
        int n = i / 28, kc = i - (i / 28) * 28;
        short8 v = *(const short8*)(w3t + n * 224 + kc * 8);
        char* dst = (char*)sB + n * 448 + (swzq28(kc, n & 7) << 4);
        *(short8*)dst = v;
    }

    // ---- A fragments in registers ----
    short8 af[7];
    {
        const int m = (llo < CM) ? llo : 0;
        const float* tnr = tn + ((size_t)g * CM + m) * CD;
        const float* tv = tvec + (size_t)g * CD;
        const float* slv = sl + (size_t)b * slStride;
#pragma unroll
        for (int ks = 0; ks < 7; ++ks) {
            const int k0 = ks * 32 + lhi * 8;
            af[ks] = pack8(xchunk(tnr, tv, slv, k0),
                           xchunk(tnr, tv, slv, k0 + 4));
        }
    }
    __syncthreads();    // the ONLY block barrier

    // ---- MFMA: K = 224 (7 k-steps), B frags just-in-time ----
    f32x4 acc[7];
#pragma unroll
    for (int nt = 0; nt < 7; ++nt) acc[nt] = (f32x4){0.f, 0.f, 0.f, 0.f};

    const char* pB = (const char*)sB;
    const int bxor = llo & 7;
#pragma unroll
    for (int ks = 0; ks < 7; ++ks) {
        const int kbq = ks * 4 + lhi;                 // 0..27
#pragma unroll
        for (int nt = 0; nt < 7; ++nt) {
            short8 bfv = *(const short8*)(pB + (nt * 16 + llo) * 448 + (swzq28(kbq, bxor) << 4));
            acc[nt] = __builtin_amdgcn_mfma_f32_16x16x32_bf16(af[ks], bfv, acc[nt], 0, 0, 0);
        }
    }

    // ---- scores: tanh + dot w4, reduce across the 16 col-lanes ----
    float s[4] = {0.f, 0.f, 0.f, 0.f};
#pragma unroll
    for (int nt = 0; nt < 7; ++nt) {
        const int n = nt * 16 + llo;
        const float w4v = (n < CD) ? w4[n] : 0.f;
#pragma unroll
        for (int r = 0; r < 4; ++r)
            s[r] = fmaf(tanhf(acc[nt][r]), w4v, s[r]);
    }
#pragma unroll
    for (int off = 1; off < 16; off <<= 1)
#pragma unroll
        for (int r = 0; r < 4; ++r) s[r] += __shfl_xor(s[r], off, 64);

    // ---- register softmax over the 12 valid rows ----
    float pmax = -1e30f;
    if (lhi < 3) pmax = fmaxf(fmaxf(s[0], s[1]), fmaxf(s[2], s[3]));
    pmax = fmaxf(pmax, __shfl_xor(pmax, 16, 64));
    pmax = fmaxf(pmax, __shfl_xor(pmax, 32, 64));
    float e[4];
#pragma unroll
    for (int r = 0; r < 4; ++r) e[r] = (lhi < 3) ? __expf(s[r] - pmax) : 0.f;
    float ps = e[0] + e[1] + e[2] + e[3];
    ps += __shfl_xor(ps, 16, 64);
    ps += __shfl_xor(ps, 32, 64);
    const float inv = 1.f / ps;
    float att[4];
#pragma unroll
    for (int r = 0; r < 4; ++r) att[r] = e[r] * inv;

    // ---- epilogue: (sum att*tn + tar0)*0.5, l2norm, 50 lanes x float2 ----
    const bool act = lane < 50;
    const int d2 = lane * 2;
    float2 tot = make_float2(0.f, 0.f);
    if (act) {
        const float* tnr = tn + (size_t)g * CM * CD + d2;
#pragma unroll
        for (int m = 0; m < CM; ++m) {
            const float at = __shfl(att[m & 3], (m >> 2) * 16, 64);
            float2 cv = *(const float2*)(tnr + m * CD);
            tot.x = fmaf(at, cv.x, tot.x);
            tot.y = fmaf(at, cv.y, tot.y);
        }
        float2 t0 = *(const float2*)(tar0 + (size_t)g * CD + d2);
        tot.x = (tot.x + t0.x) * 0.5f;
        tot.y = (tot.y + t0.y) * 0.5f;
    }
    float sq = act ? (tot.x * tot.x + tot.y * tot.y) : 0.f;
#pragma unroll
    for (int off = 32; off > 0; off >>= 1) sq += __shfl_xor(sq, off, 64);
    const float rn = 1.f / fmaxf(sqrtf(sq), 1e-12f);
    if (act) {
        tot.x *= rn; tot.y *= rn;
        *(float2*)(outp + (size_t)g * CD + d2) = tot;
    }
}

// ---------------------------------------------------------------------------
// Output assembly — nontemporal streaming stores (f32x4 native vector type).
// ---------------------------------------------------------------------------
__global__ void assemble_kernel(
    const float* __restrict__ sess_self, const float* __restrict__ emb0,
    const float* __restrict__ emb1, const float* __restrict__ tar_self,
    const float* __restrict__ T1, const float* __restrict__ T2,
    f32x4* __restrict__ out)
{
    const int LD4 = CL * CD / 4;          // 1250
    const int SLD4 = CS * LD4;            // 25000
    const int LAY0 = CB * SLD4;           // 3,200,000
    const int TOT0 = 3 * LAY0;            // 9,600,000
    const int LAY1 = CB * CS * CD / 4;    // 64,000
    const int TOT = TOT0 + 10 * LAY1;     // 10,240,000

    for (int i = blockIdx.x * blockDim.x + threadIdx.x; i < TOT;
         i += gridDim.x * blockDim.x) {
        f32x4 v;
        if (i < TOT0) {
            int layer = i / LAY0;
            int r = i - layer * LAY0;
            int b = r / SLD4;
            int r2 = r - b * SLD4;
            int ld4 = r2 % LD4;
            const float* src = (layer == 0) ? sess_self : (layer == 1) ? emb0 : emb1;
            v = ((const f32x4*)src)[b * LD4 + ld4];
        } else {
            int j = i - TOT0;
            int layer = j / LAY1;
            int r = j - layer * LAY1;
            int k = layer % 5;
            const float* src = (k == 4) ? T2 : ((k == 1) || (k == 3)) ? T1 : tar_self;
            v = ((const f32x4*)src)[r];
        }
        __builtin_nontemporal_store(v, &out[i]);
    }
}

extern "C" void kernel_launch(void* const* d_in, const int* in_sizes, int n_in,
                              void* d_out, int out_size, void* d_ws, size_t ws_size,
                              hipStream_t stream)
{
    const float* sess_self      = (const float*)d_in[0];
    const float* sess_neighbor  = (const float*)d_in[1];
    const float* sess_neighbor2 = (const float*)d_in[2];
    const float* tar_self       = (const float*)d_in[3];
    const float* tar_neighbor   = (const float*)d_in[4];
    const float* w1             = (const float*)d_in[5];  // [2, D, D]
    const float* w2             = (const float*)d_in[6];  // [2, D, 1]
    const float* w3             = (const float*)d_in[7];  // [2, 2D, D]
    const float* w4             = (const float*)d_in[8];  // [2, D, 1]
    float* out = (float*)d_out;
    float* ws  = (float*)d_ws;

    // workspace (floats): emb0 640k | emb1 640k | sn1 7.68M | T1 256k | T2 256k
    // then bf16 weights: w1t 28672 sh, w3t 50176 sh
    float* emb0 = ws;
    float* emb1 = ws + 640000;
    float* sn1  = ws + 1280000;
    float* T1   = ws + 8960000;
    float* T2   = ws + 9216000;
    unsigned short* w1t = (unsigned short*)(ws + 9472000);
    unsigned short* w3t = w1t + 28672;

    prep_weights_kernel<<<308, 256, 0, stream>>>(w1, w3, w1t, w3t);

    // merged launch (8 groups/block): L0 session attention (800 blocks, l2)
    // + 2-hop aggregation (9600 blocks) — both use layer-0 weights.
    neigh_mfma_kernel<<<10400, 256, 0, stream>>>(
        sess_self, sess_neighbor, emb0, 800, 1,
        sess_neighbor, sess_neighbor2, sn1, 0,
        w1t, w2);
    // layer 1 session attention: ctx = emb0, nbr = sn1 (800 blocks)
    neigh_mfma_kernel<<<800, 256, 0, stream>>>(
        emb0, sn1, emb1, 800, 1,
        emb0, sn1, emb1, 1,
        w1t + 112 * 128, w2 + CD);
    // target attention layer 0: t = tar_self, sl = emb0[b, l=0, :]
    tar_mfma_kernel<<<640, 256, 0, stream>>>(
        tar_self, emb0, tar_neighbor, w3t, w4, tar_self, T1, CL * CD);
    // target attention layer 1: t = T1, sl = sess_self[b, 0, :]
    tar_mfma_kernel<<<640, 256, 0, stream>>>(
        T1, sess_self, tar_neighbor, w3t + 112 * 224, w4 + CD, tar_self, T2, CL * CD);

    assemble_kernel<<<2048, 256, 0, stream>>>(
        sess_self, emb0, emb1, tar_self, T1, T2, (f32x4*)out);
}